// Round 3
// baseline (415.402 us; speedup 1.0000x reference)
//
#include <hip/hip_runtime.h>

#define S_LEN 2048
#define D_MODEL 1024
#define NH 16
#define DH 64
#define M_TOK 4096  // B*S

typedef __attribute__((ext_vector_type(8))) short bf16x8;
typedef __attribute__((ext_vector_type(4))) float f32x4;

__device__ __forceinline__ unsigned short f2bf(float f) {
  unsigned u = __float_as_uint(f);
  u += 0x7FFF + ((u >> 16) & 1);  // RNE
  return (unsigned short)(u >> 16);
}

// async 16B global->LDS (wave-uniform LDS base + lane*16 required)
__device__ __forceinline__ void gl16(const void* g, void* l) {
  __builtin_amdgcn_global_load_lds(
      (const __attribute__((address_space(1))) unsigned int*)g,
      (__attribute__((address_space(3))) unsigned int*)l, 16, 0, 0);
}

// ---------------- kernel 1: cast weights to bf16, zero energy ----------------
__global__ __launch_bounds__(256) void prep_kernel(
    const float* __restrict__ Wq, const float* __restrict__ Wk,
    const float* __restrict__ Wv, const float* __restrict__ Wo,
    unsigned short* __restrict__ wbf, float* __restrict__ energy) {
  if (blockIdx.x == 0 && threadIdx.x == 0) *energy = 0.f;
  int idx = (blockIdx.x * 256 + threadIdx.x) * 4;
  int wsel = idx >> 20;  // 1048576 elements per weight
  const float* s = (wsel == 0) ? Wq : (wsel == 1) ? Wk : (wsel == 2) ? Wv : Wo;
  int off = idx & 1048575;
  float4 v = *(const float4*)(s + off);
  ushort4 p;
  p.x = f2bf(v.x); p.y = f2bf(v.y); p.z = f2bf(v.z); p.w = f2bf(v.w);
  *(ushort4*)(wbf + idx) = p;
}

// ---------------- kernel 2: LayerNorm + phase ----------------
__device__ __forceinline__ float block_sum(float v, float* sm) {
#pragma unroll
  for (int o = 32; o > 0; o >>= 1) v += __shfl_xor(v, o, 64);
  int w = threadIdx.x >> 6;
  __syncthreads();
  if ((threadIdx.x & 63) == 0) sm[w] = v;
  __syncthreads();
  return sm[0] + sm[1] + sm[2] + sm[3];
}

__global__ __launch_bounds__(256) void ln_phase_kernel(
    const float* __restrict__ x, const float* __restrict__ Wp,
    const float* __restrict__ gamma, const float* __restrict__ beta,
    unsigned short* __restrict__ xn, float* __restrict__ cosP,
    float* __restrict__ sinP) {
  __shared__ float sm[4];
  int row = blockIdx.x;
  int tid = threadIdx.x;
  float4 v = ((const float4*)(x + (size_t)row * D_MODEL))[tid];
  float mu = block_sum(v.x + v.y + v.z + v.w, sm) * (1.0f / D_MODEL);
  float d0 = v.x - mu, d1 = v.y - mu, d2 = v.z - mu, d3 = v.w - mu;
  float var = block_sum(d0 * d0 + d1 * d1 + d2 * d2 + d3 * d3, sm) * (1.0f / D_MODEL);
  float rinv = rsqrtf(var + 1e-5f);
  float4 g = ((const float4*)gamma)[tid];
  float4 be = ((const float4*)beta)[tid];
  float n0 = d0 * rinv * g.x + be.x;
  float n1 = d1 * rinv * g.y + be.y;
  float n2 = d2 * rinv * g.z + be.z;
  float n3 = d3 * rinv * g.w + be.w;
  ushort4 p;
  p.x = f2bf(n0); p.y = f2bf(n1); p.z = f2bf(n2); p.w = f2bf(n3);
  ((ushort4*)(xn + (size_t)row * D_MODEL))[tid] = p;
  float4 wp = ((const float4*)Wp)[tid];
  float ph = block_sum(n0 * wp.x + n1 * wp.y + n2 * wp.z + n3 * wp.w, sm);
  if (tid == 0) {
    cosP[row] = cosf(ph);
    sinP[row] = sinf(ph);
  }
}

// ---------------- kernel 3: QKV GEMM (NT, bf16 MFMA, BK=64, async staging) ----
// z=0: Q = xn Wq^T   z=1: K = xn Wk^T   z=2: vT = Wv xn^T  (operands swapped so the
// C-fragment lane dim = token dim -> coalesced transposed store)
__global__ __launch_bounds__(256) void qkv_gemm_kernel(
    const unsigned short* __restrict__ xn, const unsigned short* __restrict__ wbf,
    unsigned short* __restrict__ q, unsigned short* __restrict__ k,
    unsigned short* __restrict__ vT) {
  __shared__ __align__(16) unsigned short As[128 * 64];
  __shared__ __align__(16) unsigned short Bs[128 * 64];
  int z = blockIdx.z;
  const unsigned short* Wm = wbf + (size_t)z * (D_MODEL * D_MODEL);
  const unsigned short* Ap = (z == 2) ? Wm : xn;
  const unsigned short* Bp = (z == 2) ? xn : Wm;
  int m0 = (z == 2) ? blockIdx.x * 128 : blockIdx.y * 128;
  int n0 = (z == 2) ? blockIdx.y * 128 : blockIdx.x * 128;
  int tid = threadIdx.x;
  int wave = tid >> 6, lane = tid & 63, quad = lane >> 4, l15 = lane & 15;
  int wm = (wave & 1) * 64, wn = (wave >> 1) * 64;
  f32x4 acc[4][4];
#pragma unroll
  for (int r = 0; r < 4; ++r)
#pragma unroll
    for (int c = 0; c < 4; ++c) acc[r][c] = (f32x4){0.f, 0.f, 0.f, 0.f};

  for (int k0 = 0; k0 < D_MODEL; k0 += 64) {
    __syncthreads();
#pragma unroll
    for (int t = 0; t < 4; ++t) {
      int c = t * 256 + tid;
      int r = c >> 3, p = c & 7;
      int qc = p ^ (r & 7);  // XOR swizzle: conflict-free b128 reads
      gl16(&Ap[(size_t)(m0 + r) * D_MODEL + k0 + qc * 8], &As[c * 8]);
      gl16(&Bp[(size_t)(n0 + r) * D_MODEL + k0 + qc * 8], &Bs[c * 8]);
    }
    __syncthreads();
    bf16x8 af[4][2], bfr[4][2];
#pragma unroll
    for (int r = 0; r < 4; ++r) {
      int R = wm + r * 16 + l15;
#pragma unroll
      for (int h = 0; h < 2; ++h)
        af[r][h] = *(const bf16x8*)&As[R * 64 + ((h * 4 + quad) ^ (R & 7)) * 8];
    }
#pragma unroll
    for (int c = 0; c < 4; ++c) {
      int R = wn + c * 16 + l15;
#pragma unroll
      for (int h = 0; h < 2; ++h)
        bfr[c][h] = *(const bf16x8*)&Bs[R * 64 + ((h * 4 + quad) ^ (R & 7)) * 8];
    }
#pragma unroll
    for (int h = 0; h < 2; ++h)
#pragma unroll
      for (int r = 0; r < 4; ++r)
#pragma unroll
        for (int c = 0; c < 4; ++c)
          acc[r][c] = __builtin_amdgcn_mfma_f32_16x16x32_bf16(af[r][h], bfr[c][h], acc[r][c], 0, 0, 0);
  }
#pragma unroll
  for (int r = 0; r < 4; ++r) {
#pragma unroll
    for (int c = 0; c < 4; ++c) {
#pragma unroll
      for (int rr = 0; rr < 4; ++rr) {
        if (z == 2) {
          int e = m0 + wm + r * 16 + quad * 4 + rr;   // row of Wv = output channel
          int tok = n0 + wn + c * 16 + l15;           // token (lane dim -> coalesced)
          int hh = e >> 6, d = e & 63;
          int bb = tok >> 11, ss = tok & (S_LEN - 1);
          vT[(((size_t)(bb * NH + hh)) * DH + d) * S_LEN + ss] = f2bf(acc[r][c][rr]);
        } else {
          int tok = m0 + wm + r * 16 + quad * 4 + rr;
          int e = n0 + wn + c * 16 + l15;
          int hh = e >> 6, d = e & 63;
          int bb = tok >> 11, ss = tok & (S_LEN - 1);
          unsigned short val = f2bf(acc[r][c][rr] * ((z == 0) ? 0.125f : 1.0f));
          unsigned short* dst = (z == 0) ? q : k;
          dst[(((size_t)(bb * NH + hh)) * S_LEN + ss) * DH + d] = val;
        }
      }
    }
  }
}

// ---------------- kernel 4: flash attention with resonance ----------------
// Barrier-free KV loop: K/V fragments straight from global (L1/L2-resident),
// fixed-max softmax (scores bounded), row sums via ones-column MFMA.
__global__ __launch_bounds__(256) void attn_kernel(
    const unsigned short* __restrict__ q, const unsigned short* __restrict__ kk,
    const unsigned short* __restrict__ vT, const float* __restrict__ cosP,
    const float* __restrict__ sinP, const float* __restrict__ carrier,
    const float* __restrict__ lamp, unsigned short* __restrict__ outw,
    float* __restrict__ energy) {
  __shared__ __align__(16) unsigned short Ps[4][16 * 72];  // per-wave P transpose
  __shared__ float er[4];
  int qt = blockIdx.x, h = blockIdx.y, b = blockIdx.z;
  int bh = b * NH + h;
  int tid = threadIdx.x, wave = tid >> 6, lane = tid & 63;
  int quad = lane >> 4, l15 = lane & 15;
  float hl = 0.5f * lamp[0];
  float ch = cosf(carrier[h]), sh = sinf(carrier[h]);
  const unsigned short* qb = q + ((size_t)bh * S_LEN + qt * 64) * DH;
  const unsigned short* kb = kk + (size_t)bh * S_LEN * DH;
  const unsigned short* vb = vT + (size_t)bh * DH * S_LEN;
  const float* cpb = cosP + b * S_LEN;
  const float* spb = sinP + b * S_LEN;

  int qrow = wave * 16 + l15;
  bf16x8 aQ0 = *(const bf16x8*)(qb + qrow * DH + quad * 8);
  bf16x8 aQ1 = *(const bf16x8*)(qb + qrow * DH + 32 + quad * 8);

  const short oneb = 0x3F80;  // bf16 1.0
  bf16x8 vone = {oneb, oneb, oneb, oneb, oneb, oneb, oneb, oneb};

  float cI[4], sI[4];
  f32x4 o[4], oS;
#pragma unroll
  for (int r = 0; r < 4; ++r) {
    int il = qt * 64 + wave * 16 + quad * 4 + r;
    cI[r] = hl * cpb[il];
    sI[r] = hl * spb[il];
    o[r] = (f32x4){0.f, 0.f, 0.f, 0.f};
  }
  oS = (f32x4){0.f, 0.f, 0.f, 0.f};

  for (int j0 = 0; j0 < S_LEN; j0 += 64) {
    float Sc[4][4];
#pragma unroll
    for (int cg = 0; cg < 4; ++cg) {
      int row = j0 + cg * 16 + l15;
      bf16x8 b0 = *(const bf16x8*)&kb[(size_t)row * DH + quad * 8];
      bf16x8 b1 = *(const bf16x8*)&kb[(size_t)row * DH + 32 + quad * 8];
      f32x4 cfr = (f32x4){0.f, 0.f, 0.f, 0.f};
      cfr = __builtin_amdgcn_mfma_f32_16x16x32_bf16(aQ0, b0, cfr, 0, 0, 0);
      cfr = __builtin_amdgcn_mfma_f32_16x16x32_bf16(aQ1, b1, cfr, 0, 0, 0);
      float cj = cpb[row], sj = spb[row];
#pragma unroll
      for (int r = 0; r < 4; ++r) Sc[cg][r] = cfr[r] + cI[r] * cj + sI[r] * sj;
    }
    // P = exp(S) (fixed max: scores bounded ~|2.6|), transpose to A-layout
#pragma unroll
    for (int cg = 0; cg < 4; ++cg)
#pragma unroll
      for (int r = 0; r < 4; ++r)
        Ps[wave][(quad * 4 + r) * 72 + cg * 16 + l15] = f2bf(__expf(Sc[cg][r]));
#pragma unroll
    for (int hh2 = 0; hh2 < 2; ++hh2) {
      bf16x8 aP = *(const bf16x8*)&Ps[wave][l15 * 72 + hh2 * 32 + quad * 8];
#pragma unroll
      for (int dg = 0; dg < 4; ++dg) {
        bf16x8 bV = *(const bf16x8*)&vb[(size_t)(dg * 16 + l15) * S_LEN + j0 + hh2 * 32 + quad * 8];
        o[dg] = __builtin_amdgcn_mfma_f32_16x16x32_bf16(aP, bV, o[dg], 0, 0, 0);
      }
      oS = __builtin_amdgcn_mfma_f32_16x16x32_bf16(aP, vone, oS, 0, 0, 0);
    }
  }
  // epilogue: normalize (l_i from ones-MFMA), gate, store, energy
  float esum = 0.f;
#pragma unroll
  for (int r = 0; r < 4; ++r) {
    int il = wave * 16 + quad * 4 + r;
    int srow = qt * 64 + il;
    float cp = cpb[srow], sp = spb[srow];
    float gate = 0.5f + 0.5f * (cp * ch + sp * sh);
    float gl = gate / oS[r];
    int tok = b * S_LEN + srow;
#pragma unroll
    for (int dg = 0; dg < 4; ++dg) {
      float val = o[dg][r] * gl;
      esum += fabsf(val);
      outw[(size_t)tok * D_MODEL + h * DH + dg * 16 + l15] = f2bf(val);
    }
  }
#pragma unroll
  for (int off = 32; off > 0; off >>= 1) esum += __shfl_xor(esum, off, 64);
  if (lane == 0) er[wave] = esum;
  __syncthreads();
  if (tid == 0) atomicAdd(energy, er[0] + er[1] + er[2] + er[3]);
}

// ---------------- kernel 5: output projection + residual (BK=64) ----------------
__global__ __launch_bounds__(256) void out_gemm_kernel(
    const unsigned short* __restrict__ A, const unsigned short* __restrict__ Wo,
    const float* __restrict__ x, float* __restrict__ y) {
  __shared__ __align__(16) unsigned short As[128 * 64];
  __shared__ __align__(16) unsigned short Bs[128 * 64];
  int tid = threadIdx.x;
  int wave = tid >> 6, lane = tid & 63, quad = lane >> 4, l15 = lane & 15;
  int wm = (wave & 1) * 64, wn = (wave >> 1) * 64;
  int m0 = blockIdx.y * 128, n0 = blockIdx.x * 128;
  f32x4 acc[4][4];
#pragma unroll
  for (int r = 0; r < 4; ++r)
#pragma unroll
    for (int c = 0; c < 4; ++c) acc[r][c] = (f32x4){0.f, 0.f, 0.f, 0.f};

  for (int k0 = 0; k0 < D_MODEL; k0 += 64) {
    __syncthreads();
#pragma unroll
    for (int t = 0; t < 4; ++t) {
      int c = t * 256 + tid;
      int r = c >> 3, p = c & 7;
      int qc = p ^ (r & 7);
      gl16(&A[(size_t)(m0 + r) * D_MODEL + k0 + qc * 8], &As[c * 8]);
      gl16(&Wo[(size_t)(n0 + r) * D_MODEL + k0 + qc * 8], &Bs[c * 8]);
    }
    __syncthreads();
    bf16x8 af[4][2], bfr[4][2];
#pragma unroll
    for (int r = 0; r < 4; ++r) {
      int R = wm + r * 16 + l15;
#pragma unroll
      for (int h = 0; h < 2; ++h)
        af[r][h] = *(const bf16x8*)&As[R * 64 + ((h * 4 + quad) ^ (R & 7)) * 8];
    }
#pragma unroll
    for (int c = 0; c < 4; ++c) {
      int R = wn + c * 16 + l15;
#pragma unroll
      for (int h = 0; h < 2; ++h)
        bfr[c][h] = *(const bf16x8*)&Bs[R * 64 + ((h * 4 + quad) ^ (R & 7)) * 8];
    }
#pragma unroll
    for (int h = 0; h < 2; ++h)
#pragma unroll
      for (int r = 0; r < 4; ++r)
#pragma unroll
        for (int c = 0; c < 4; ++c)
          acc[r][c] = __builtin_amdgcn_mfma_f32_16x16x32_bf16(af[r][h], bfr[c][h], acc[r][c], 0, 0, 0);
  }
#pragma unroll
  for (int r = 0; r < 4; ++r) {
#pragma unroll
    for (int c = 0; c < 4; ++c) {
      int dcol = n0 + wn + c * 16 + l15;
#pragma unroll
      for (int rr = 0; rr < 4; ++rr) {
        int tok = m0 + wm + r * 16 + quad * 4 + rr;
        size_t idx = (size_t)tok * D_MODEL + dcol;
        y[idx] = x[idx] + acc[r][c][rr];
      }
    }
  }
}

extern "C" void kernel_launch(void* const* d_in, const int* in_sizes, int n_in,
                              void* d_out, int out_size, void* d_ws, size_t ws_size,
                              hipStream_t stream) {
  const float* x = (const float*)d_in[0];
  const float* Wq = (const float*)d_in[1];
  const float* Wk = (const float*)d_in[2];
  const float* Wv = (const float*)d_in[3];
  const float* Wo = (const float*)d_in[4];
  const float* Wp = (const float*)d_in[5];
  const float* gamma = (const float*)d_in[6];
  const float* beta = (const float*)d_in[7];
  const float* carrier = (const float*)d_in[8];
  const float* lam = (const float*)d_in[9];

  char* ws = (char*)d_ws;
  const size_t MB = 1024 * 1024;
  unsigned short* wbf = (unsigned short*)(ws);             // 8 MB: Wq|Wk|Wv|Wo bf16
  unsigned short* xn = (unsigned short*)(ws + 8 * MB);     // 8 MB
  unsigned short* qq = (unsigned short*)(ws + 16 * MB);    // 8 MB (B,H,S,dh)
  unsigned short* kk = (unsigned short*)(ws + 24 * MB);    // 8 MB (B,H,S,dh)
  unsigned short* vT = (unsigned short*)(ws + 32 * MB);    // 8 MB (B,H,dh,S)
  unsigned short* outw = (unsigned short*)(ws + 40 * MB);  // 8 MB (tok, e)
  float* cosP = (float*)(ws + 48 * MB);                    // 16 KB
  float* sinP = (float*)(ws + 48 * MB + 16 * 1024);        // 16 KB

  float* y = (float*)d_out;
  float* energy = y + (out_size - 1);

  prep_kernel<<<4096, 256, 0, stream>>>(Wq, Wk, Wv, Wo, wbf, energy);
  ln_phase_kernel<<<M_TOK, 256, 0, stream>>>(x, Wp, gamma, beta, xn, cosP, sinP);
  qkv_gemm_kernel<<<dim3(8, 32, 3), 256, 0, stream>>>(xn, wbf, qq, kk, vT);
  attn_kernel<<<dim3(32, 16, 2), 256, 0, stream>>>(qq, kk, vT, cosP, sinP, carrier,
                                                   lam, outw, energy);
  out_gemm_kernel<<<dim3(8, 32), 256, 0, stream>>>(outw, wbf + 3 * D_MODEL * D_MODEL,
                                                   x, y);
}

// Round 4
// 242.586 us; speedup vs baseline: 1.7124x; 1.7124x over previous
//
#include <hip/hip_runtime.h>
#include <hip/hip_bf16.h>

#define S_LEN 2048
#define D_MODEL 1024
#define NH 16
#define DH 64
#define M_TOK 4096  // B*S
#define DK 80       // K' width: 64 d + cos,sin + 14 zero pad

typedef __attribute__((ext_vector_type(8))) short bf16x8;
typedef __attribute__((ext_vector_type(4))) float f32x4;
typedef __attribute__((ext_vector_type(16))) float f32x16;

#define LOG2E 1.4426950408889634f

__device__ __forceinline__ unsigned short f2bf(float f) {
  unsigned u = __float_as_uint(f);
  u += 0x7FFF + ((u >> 16) & 1);  // RNE
  return (unsigned short)(u >> 16);
}

// async 16B global->LDS (LDS dst must be wave-uniform base + lane*16)
__device__ __forceinline__ void gl16(const void* g, void* l) {
  __builtin_amdgcn_global_load_lds(
      (const __attribute__((address_space(1))) unsigned int*)g,
      (__attribute__((address_space(3))) unsigned int*)l, 16, 0, 0);
}

// ---------------- kernel 1: cast weights to bf16, zero energy ----------------
__global__ __launch_bounds__(256) void prep_kernel(
    const float* __restrict__ Wq, const float* __restrict__ Wk,
    const float* __restrict__ Wv, const float* __restrict__ Wo,
    unsigned short* __restrict__ wbf, float* __restrict__ energy) {
  if (blockIdx.x == 0 && threadIdx.x == 0) *energy = 0.f;
  int idx = (blockIdx.x * 256 + threadIdx.x) * 4;
  int wsel = idx >> 20;
  const float* s = (wsel == 0) ? Wq : (wsel == 1) ? Wk : (wsel == 2) ? Wv : Wo;
  int off = idx & 1048575;
  float4 v = *(const float4*)(s + off);
  ushort4 p;
  p.x = f2bf(v.x); p.y = f2bf(v.y); p.z = f2bf(v.z); p.w = f2bf(v.w);
  *(ushort4*)(wbf + idx) = p;
}

// ---------------- kernel 2: LayerNorm + phase ----------------
__device__ __forceinline__ float block_sum(float v, float* sm) {
#pragma unroll
  for (int o = 32; o > 0; o >>= 1) v += __shfl_xor(v, o, 64);
  int w = threadIdx.x >> 6;
  __syncthreads();
  if ((threadIdx.x & 63) == 0) sm[w] = v;
  __syncthreads();
  return sm[0] + sm[1] + sm[2] + sm[3];
}

__global__ __launch_bounds__(256) void ln_phase_kernel(
    const float* __restrict__ x, const float* __restrict__ Wp,
    const float* __restrict__ gamma, const float* __restrict__ beta,
    unsigned short* __restrict__ xn, float* __restrict__ cosP,
    float* __restrict__ sinP) {
  __shared__ float sm[4];
  int row = blockIdx.x;
  int tid = threadIdx.x;
  float4 v = ((const float4*)(x + (size_t)row * D_MODEL))[tid];
  float mu = block_sum(v.x + v.y + v.z + v.w, sm) * (1.0f / D_MODEL);
  float d0 = v.x - mu, d1 = v.y - mu, d2 = v.z - mu, d3 = v.w - mu;
  float var = block_sum(d0 * d0 + d1 * d1 + d2 * d2 + d3 * d3, sm) * (1.0f / D_MODEL);
  float rinv = rsqrtf(var + 1e-5f);
  float4 g = ((const float4*)gamma)[tid];
  float4 be = ((const float4*)beta)[tid];
  float n0 = d0 * rinv * g.x + be.x;
  float n1 = d1 * rinv * g.y + be.y;
  float n2 = d2 * rinv * g.z + be.z;
  float n3 = d3 * rinv * g.w + be.w;
  ushort4 p;
  p.x = f2bf(n0); p.y = f2bf(n1); p.z = f2bf(n2); p.w = f2bf(n3);
  ((ushort4*)(xn + (size_t)row * D_MODEL))[tid] = p;
  float4 wp = ((const float4*)Wp)[tid];
  float ph = block_sum(n0 * wp.x + n1 * wp.y + n2 * wp.z + n3 * wp.w, sm);
  if (tid == 0) {
    cosP[row] = cosf(ph);
    sinP[row] = sinf(ph);
  }
}

// ---------------- kernel 2b: fill K' phase columns (64..79) ----------------
__global__ __launch_bounds__(256) void phase_fill_kernel(
    const float* __restrict__ cosP, const float* __restrict__ sinP,
    unsigned short* __restrict__ kk80) {
  int gid = blockIdx.x * 256 + threadIdx.x;  // 65536 (bh,s) rows
  int s = gid & (S_LEN - 1);
  int bh = gid >> 11;
  int b = bh >> 4;
  int tok = b * S_LEN + s;
  unsigned int w0 = (unsigned int)f2bf(cosP[tok]) | ((unsigned int)f2bf(sinP[tok]) << 16);
  int4 lo = make_int4((int)w0, 0, 0, 0);
  int4 hi = make_int4(0, 0, 0, 0);
  *(int4*)(kk80 + (size_t)gid * DK + 64) = lo;
  *(int4*)(kk80 + (size_t)gid * DK + 72) = hi;
}

// ---------------- kernel 3: QKV GEMM (NT, bf16 MFMA, BK=64, async staging) ----
// z=0: Q = xn Wq^T (scaled 0.125*log2e)  z=1: K -> kk80 (stride 80)
// z=2: vT = Wv xn^T (operand swap -> coalesced transposed store)
__global__ __launch_bounds__(256) void qkv_gemm_kernel(
    const unsigned short* __restrict__ xn, const unsigned short* __restrict__ wbf,
    unsigned short* __restrict__ q, unsigned short* __restrict__ kk80,
    unsigned short* __restrict__ vT) {
  __shared__ __align__(16) unsigned short As[128 * 64];
  __shared__ __align__(16) unsigned short Bs[128 * 64];
  int z = blockIdx.z;
  const unsigned short* Wm = wbf + (size_t)z * (D_MODEL * D_MODEL);
  const unsigned short* Ap = (z == 2) ? Wm : xn;
  const unsigned short* Bp = (z == 2) ? xn : Wm;
  int m0 = (z == 2) ? blockIdx.x * 128 : blockIdx.y * 128;
  int n0 = (z == 2) ? blockIdx.y * 128 : blockIdx.x * 128;
  int tid = threadIdx.x;
  int wave = tid >> 6, lane = tid & 63, quad = lane >> 4, l15 = lane & 15;
  int wm = (wave & 1) * 64, wn = (wave >> 1) * 64;
  f32x4 acc[4][4];
#pragma unroll
  for (int r = 0; r < 4; ++r)
#pragma unroll
    for (int c = 0; c < 4; ++c) acc[r][c] = (f32x4){0.f, 0.f, 0.f, 0.f};

  for (int k0 = 0; k0 < D_MODEL; k0 += 64) {
    __syncthreads();
#pragma unroll
    for (int t = 0; t < 4; ++t) {
      int c = t * 256 + tid;
      int r = c >> 3, p = c & 7;
      int qc = p ^ (r & 7);
      gl16(&Ap[(size_t)(m0 + r) * D_MODEL + k0 + qc * 8], &As[c * 8]);
      gl16(&Bp[(size_t)(n0 + r) * D_MODEL + k0 + qc * 8], &Bs[c * 8]);
    }
    __syncthreads();
    bf16x8 af[4][2], bfr[4][2];
#pragma unroll
    for (int r = 0; r < 4; ++r) {
      int R = wm + r * 16 + l15;
#pragma unroll
      for (int h = 0; h < 2; ++h)
        af[r][h] = *(const bf16x8*)&As[R * 64 + ((h * 4 + quad) ^ (R & 7)) * 8];
    }
#pragma unroll
    for (int c = 0; c < 4; ++c) {
      int R = wn + c * 16 + l15;
#pragma unroll
      for (int h = 0; h < 2; ++h)
        bfr[c][h] = *(const bf16x8*)&Bs[R * 64 + ((h * 4 + quad) ^ (R & 7)) * 8];
    }
#pragma unroll
    for (int h = 0; h < 2; ++h)
#pragma unroll
      for (int r = 0; r < 4; ++r)
#pragma unroll
        for (int c = 0; c < 4; ++c)
          acc[r][c] = __builtin_amdgcn_mfma_f32_16x16x32_bf16(af[r][h], bfr[c][h], acc[r][c], 0, 0, 0);
  }
#pragma unroll
  for (int r = 0; r < 4; ++r) {
#pragma unroll
    for (int c = 0; c < 4; ++c) {
#pragma unroll
      for (int rr = 0; rr < 4; ++rr) {
        if (z == 2) {
          int e = m0 + wm + r * 16 + quad * 4 + rr;
          int tok = n0 + wn + c * 16 + l15;
          int hh = e >> 6, d = e & 63;
          int bb = tok >> 11, ss = tok & (S_LEN - 1);
          vT[(((size_t)(bb * NH + hh)) * DH + d) * S_LEN + ss] = f2bf(acc[r][c][rr]);
        } else {
          int tok = m0 + wm + r * 16 + quad * 4 + rr;
          int e = n0 + wn + c * 16 + l15;
          int hh = e >> 6, d = e & 63;
          int bb = tok >> 11, ss = tok & (S_LEN - 1);
          if (z == 0) {
            unsigned short val = f2bf(acc[r][c][rr] * (0.125f * LOG2E));
            q[(((size_t)(bb * NH + hh)) * S_LEN + ss) * DH + d] = val;
          } else {
            kk80[(((size_t)(bb * NH + hh)) * S_LEN + ss) * DK + d] = f2bf(acc[r][c][rr]);
          }
        }
      }
    }
  }
}

// ---------------- kernel 4: flash attention, 32x32 MFMA, S^T formulation ------
// S^T = K'.Q'^T (resonance folded as 2 extra K-dims), exp2 fixed-max softmax,
// per-lane row sums, P packed->LDS->A-frags, O = P.V (V^T staged).
__global__ __launch_bounds__(256) void attn_kernel(
    const unsigned short* __restrict__ q, const unsigned short* __restrict__ kk80,
    const unsigned short* __restrict__ vT, const float* __restrict__ cosP,
    const float* __restrict__ sinP, const float* __restrict__ carrier,
    const float* __restrict__ lamp, unsigned short* __restrict__ outw,
    float* __restrict__ energy) {
  __shared__ __align__(16) unsigned short Ks[640 * 8];  // 64 rows x 10 chunks (K')
  __shared__ __align__(16) unsigned short Vs[512 * 8];  // 64 d-rows x 8 chunks
  __shared__ __align__(16) unsigned int Ps[4][32 * 34]; // per-wave P, stride 34 dw
  __shared__ float Lr[4][32];
  __shared__ float er[4];
  int qt = blockIdx.x, h = blockIdx.y, b = blockIdx.z;
  int bh = b * NH + h;
  int tid = threadIdx.x, wave = tid >> 6, lane = tid & 63;
  int half = lane >> 5, l31 = lane & 31;

  const unsigned short* kb = kk80 + (size_t)bh * S_LEN * DK;
  const unsigned short* vb = vT + (size_t)bh * DH * S_LEN;
  int qrow = qt * 128 + wave * 32 + l31;

  // Q fragments: B[n=i][k=d], d-blocks 0..3 from global, block 4 = phase cols
  bf16x8 bQ[5];
  {
    const unsigned short* qp = q + ((size_t)bh * S_LEN + qrow) * DH;
#pragma unroll
    for (int db = 0; db < 4; ++db)
      bQ[db] = *(const bf16x8*)(qp + db * 16 + half * 8);
    bf16x8 z8 = {0, 0, 0, 0, 0, 0, 0, 0};
    if (half == 0) {
      float hl2 = 0.5f * lamp[0] * LOG2E;
      z8[0] = (short)f2bf(hl2 * cosP[b * S_LEN + qrow]);
      z8[1] = (short)f2bf(hl2 * sinP[b * S_LEN + qrow]);
    }
    bQ[4] = z8;
  }

  f32x16 O0 = {}, O1 = {};
  float l_i = 0.f;

  for (int j0 = 0; j0 < S_LEN; j0 += 64) {
    __syncthreads();
    // stage K' (640 chunks, rotate-swizzled) and V (512 chunks, XOR-swizzled)
#pragma unroll
    for (int t = 0; t < 2; ++t) {
      int cc = t * 256 + tid;
      int r = (cc * 205) >> 11;  // cc/10
      int p = cc - r * 10;
      int g = p + ((r >> 2) & 3);
      if (g >= 10) g -= 10;
      gl16(&kb[(size_t)(j0 + r) * DK + g * 8], (unsigned short*)Ks + cc * 8);
    }
    if (tid < 128) {
      int cc = 512 + tid;
      int r = (cc * 205) >> 11;
      int p = cc - r * 10;
      int g = p + ((r >> 2) & 3);
      if (g >= 10) g -= 10;
      gl16(&kb[(size_t)(j0 + r) * DK + g * 8], (unsigned short*)Ks + cc * 8);
    }
#pragma unroll
    for (int t = 0; t < 2; ++t) {
      int cc = t * 256 + tid;
      int r = cc >> 3, p = cc & 7;
      int g = p ^ (r & 7);
      gl16(&vb[(size_t)r * S_LEN + j0 + g * 8], (unsigned short*)Vs + cc * 8);
    }
    __syncthreads();

    // S^T: A = K' (m=j), B = Q' (n=i); 2 j-subtiles x 5 d-blocks
    f32x16 Sf[2];
#pragma unroll
    for (int sj = 0; sj < 2; ++sj) {
      Sf[sj] = (f32x16){};
      int r = sj * 32 + l31;
      int rot = (r >> 2) & 3;
#pragma unroll
      for (int db = 0; db < 5; ++db) {
        int p = db * 2 + half - rot;
        if (p < 0) p += 10;
        bf16x8 aK = *(const bf16x8*)((const unsigned short*)Ks + (r * 10 + p) * 8);
        Sf[sj] = __builtin_amdgcn_mfma_f32_32x32x16_bf16(aK, bQ[db], Sf[sj], 0, 0, 0);
      }
    }

    // exp2 (fixed max), per-lane row-sum accumulate, pack j-pairs -> Ps
#pragma unroll
    for (int sj = 0; sj < 2; ++sj) {
#pragma unroll
      for (int rr = 0; rr < 8; ++rr) {
        float e0 = exp2f(Sf[sj][rr * 2 + 0]);
        float e1 = exp2f(Sf[sj][rr * 2 + 1]);
        l_i += e0 + e1;
        __hip_bfloat162 pk = __float22bfloat162_rn(float2{e0, e1});
        int jd = sj * 16 + (rr >> 1) * 4 + half * 2 + (rr & 1);
        Ps[wave][l31 * 34 + jd] = *(unsigned int*)&pk;
      }
    }

    // O += P.V : A = P (m=i) from Ps, B = V^T (n=d) from Vs
#pragma unroll
    for (int jb = 0; jb < 4; ++jb) {
      const unsigned int* pp = &Ps[wave][l31 * 34 + jb * 8 + half * 4];
      uint2 a0 = *(const uint2*)pp;
      uint2 a1 = *(const uint2*)(pp + 2);
      union { unsigned int u[4]; bf16x8 v; } cvt;
      cvt.u[0] = a0.x; cvt.u[1] = a0.y; cvt.u[2] = a1.x; cvt.u[3] = a1.y;
      {
        int rv = l31;
        int p = (jb * 2 + half) ^ (rv & 7);
        bf16x8 bV = *(const bf16x8*)((const unsigned short*)Vs + (rv * 8 + p) * 8);
        O0 = __builtin_amdgcn_mfma_f32_32x32x16_bf16(cvt.v, bV, O0, 0, 0, 0);
      }
      {
        int rv = 32 + l31;
        int p = (jb * 2 + half) ^ (rv & 7);
        bf16x8 bV = *(const bf16x8*)((const unsigned short*)Vs + (rv * 8 + p) * 8);
        O1 = __builtin_amdgcn_mfma_f32_32x32x16_bf16(cvt.v, bV, O1, 0, 0, 0);
      }
    }
  }

  // epilogue: cross-half l reduce, gate, normalize, store, energy
  l_i += __shfl_xor(l_i, 32, 64);
  Lr[wave][l31] = l_i;
  float ch = cosf(carrier[h]), sh = sinf(carrier[h]);
  float esum = 0.f;
#pragma unroll
  for (int reg = 0; reg < 16; ++reg) {
    int ir = (reg & 3) + 8 * (reg >> 2) + 4 * half;
    int srow = qt * 128 + wave * 32 + ir;
    float cp = cosP[b * S_LEN + srow], sp = sinP[b * S_LEN + srow];
    float gate = 0.5f + 0.5f * (cp * ch + sp * sh);
    float gl = gate / Lr[wave][ir];
    size_t tok = (size_t)b * S_LEN + srow;
    float v0 = O0[reg] * gl, v1 = O1[reg] * gl;
    esum += fabsf(v0) + fabsf(v1);
    outw[tok * D_MODEL + h * DH + l31] = f2bf(v0);
    outw[tok * D_MODEL + h * DH + 32 + l31] = f2bf(v1);
  }
#pragma unroll
  for (int off = 32; off > 0; off >>= 1) esum += __shfl_xor(esum, off, 64);
  if (lane == 0) er[wave] = esum;
  __syncthreads();
  if (tid == 0) atomicAdd(energy, er[0] + er[1] + er[2] + er[3]);
}

// ---------------- kernel 5: output projection + residual (BK=64) ----------------
__global__ __launch_bounds__(256) void out_gemm_kernel(
    const unsigned short* __restrict__ A, const unsigned short* __restrict__ Wo,
    const float* __restrict__ x, float* __restrict__ y) {
  __shared__ __align__(16) unsigned short As[128 * 64];
  __shared__ __align__(16) unsigned short Bs[128 * 64];
  int tid = threadIdx.x;
  int wave = tid >> 6, lane = tid & 63, quad = lane >> 4, l15 = lane & 15;
  int wm = (wave & 1) * 64, wn = (wave >> 1) * 64;
  int m0 = blockIdx.y * 128, n0 = blockIdx.x * 128;
  f32x4 acc[4][4];
#pragma unroll
  for (int r = 0; r < 4; ++r)
#pragma unroll
    for (int c = 0; c < 4; ++c) acc[r][c] = (f32x4){0.f, 0.f, 0.f, 0.f};

  for (int k0 = 0; k0 < D_MODEL; k0 += 64) {
    __syncthreads();
#pragma unroll
    for (int t = 0; t < 4; ++t) {
      int c = t * 256 + tid;
      int r = c >> 3, p = c & 7;
      int qc = p ^ (r & 7);
      gl16(&A[(size_t)(m0 + r) * D_MODEL + k0 + qc * 8], &As[c * 8]);
      gl16(&Wo[(size_t)(n0 + r) * D_MODEL + k0 + qc * 8], &Bs[c * 8]);
    }
    __syncthreads();
    bf16x8 af[4][2], bfr[4][2];
#pragma unroll
    for (int r = 0; r < 4; ++r) {
      int R = wm + r * 16 + l15;
#pragma unroll
      for (int h = 0; h < 2; ++h)
        af[r][h] = *(const bf16x8*)&As[R * 64 + ((h * 4 + quad) ^ (R & 7)) * 8];
    }
#pragma unroll
    for (int c = 0; c < 4; ++c) {
      int R = wn + c * 16 + l15;
#pragma unroll
      for (int h = 0; h < 2; ++h)
        bfr[c][h] = *(const bf16x8*)&Bs[R * 64 + ((h * 4 + quad) ^ (R & 7)) * 8];
    }
#pragma unroll
    for (int h = 0; h < 2; ++h)
#pragma unroll
      for (int r = 0; r < 4; ++r)
#pragma unroll
        for (int c = 0; c < 4; ++c)
          acc[r][c] = __builtin_amdgcn_mfma_f32_16x16x32_bf16(af[r][h], bfr[c][h], acc[r][c], 0, 0, 0);
  }
#pragma unroll
  for (int r = 0; r < 4; ++r) {
#pragma unroll
    for (int c = 0; c < 4; ++c) {
      int dcol = n0 + wn + c * 16 + l15;
#pragma unroll
      for (int rr = 0; rr < 4; ++rr) {
        int tok = m0 + wm + r * 16 + quad * 4 + rr;
        size_t idx = (size_t)tok * D_MODEL + dcol;
        y[idx] = x[idx] + acc[r][c][rr];
      }
    }
  }
}

extern "C" void kernel_launch(void* const* d_in, const int* in_sizes, int n_in,
                              void* d_out, int out_size, void* d_ws, size_t ws_size,
                              hipStream_t stream) {
  const float* x = (const float*)d_in[0];
  const float* Wq = (const float*)d_in[1];
  const float* Wk = (const float*)d_in[2];
  const float* Wv = (const float*)d_in[3];
  const float* Wo = (const float*)d_in[4];
  const float* Wp = (const float*)d_in[5];
  const float* gamma = (const float*)d_in[6];
  const float* beta = (const float*)d_in[7];
  const float* carrier = (const float*)d_in[8];
  const float* lam = (const float*)d_in[9];

  char* ws = (char*)d_ws;
  const size_t MB = 1024 * 1024;
  unsigned short* wbf = (unsigned short*)(ws);            // 8 MB
  unsigned short* xn = (unsigned short*)(ws + 8 * MB);    // 8 MB (aliased: outw)
  unsigned short* qq = (unsigned short*)(ws + 16 * MB);   // 8 MB (bh,S,64)
  unsigned short* kk80 = (unsigned short*)(ws + 24 * MB); // 10 MB (bh,S,80)
  unsigned short* vT = (unsigned short*)(ws + 34 * MB);   // 8 MB (bh,64,S)
  float* cosP = (float*)(ws + 42 * MB);                   // 16 KB
  float* sinP = (float*)(ws + 42 * MB + 16 * 1024);       // 16 KB
  unsigned short* outw = xn;  // attn runs after qkv consumed xn

  float* y = (float*)d_out;
  float* energy = y + (out_size - 1);

  prep_kernel<<<4096, 256, 0, stream>>>(Wq, Wk, Wv, Wo, wbf, energy);
  ln_phase_kernel<<<M_TOK, 256, 0, stream>>>(x, Wp, gamma, beta, xn, cosP, sinP);
  phase_fill_kernel<<<256, 256, 0, stream>>>(cosP, sinP, kk80);
  qkv_gemm_kernel<<<dim3(8, 32, 3), 256, 0, stream>>>(xn, wbf, qq, kk80, vT);
  attn_kernel<<<dim3(16, 16, 2), 256, 0, stream>>>(qq, kk80, vT, cosP, sinP,
                                                   carrier, lam, outw, energy);
  out_gemm_kernel<<<dim3(8, 32), 256, 0, stream>>>(outw, wbf + 3 * D_MODEL * D_MODEL,
                                                   x, y);
}

// Round 5
// 230.865 us; speedup vs baseline: 1.7993x; 1.0508x over previous
//
#include <hip/hip_runtime.h>
#include <hip/hip_bf16.h>

#define S_LEN 2048
#define D_MODEL 1024
#define NH 16
#define DH 64
#define M_TOK 4096  // B*S
#define DK 80       // K' width: 64 d + cos,sin + 14 zero pad

typedef __attribute__((ext_vector_type(8))) short bf16x8;
typedef __attribute__((ext_vector_type(4))) float f32x4;
typedef __attribute__((ext_vector_type(16))) float f32x16;

#define LOG2E 1.4426950408889634f

__device__ __forceinline__ unsigned short f2bf(float f) {
  unsigned u = __float_as_uint(f);
  u += 0x7FFF + ((u >> 16) & 1);  // RNE
  return (unsigned short)(u >> 16);
}

// async 16B global->LDS (LDS dst must be wave-uniform base + lane*16)
__device__ __forceinline__ void gl16(const void* g, void* l) {
  __builtin_amdgcn_global_load_lds(
      (const __attribute__((address_space(1))) unsigned int*)g,
      (__attribute__((address_space(3))) unsigned int*)l, 16, 0, 0);
}

// ---------------- kernel 1: cast weights to bf16, zero energy ----------------
__global__ __launch_bounds__(256) void prep_kernel(
    const float* __restrict__ Wq, const float* __restrict__ Wk,
    const float* __restrict__ Wv, const float* __restrict__ Wo,
    unsigned short* __restrict__ wbf, float* __restrict__ energy) {
  if (blockIdx.x == 0 && threadIdx.x == 0) *energy = 0.f;
  int idx = (blockIdx.x * 256 + threadIdx.x) * 4;
  int wsel = idx >> 20;
  const float* s = (wsel == 0) ? Wq : (wsel == 1) ? Wk : (wsel == 2) ? Wv : Wo;
  int off = idx & 1048575;
  float4 v = *(const float4*)(s + off);
  ushort4 p;
  p.x = f2bf(v.x); p.y = f2bf(v.y); p.z = f2bf(v.z); p.w = f2bf(v.w);
  *(ushort4*)(wbf + idx) = p;
}

// ---------------- kernel 2: LayerNorm + phase ----------------
__device__ __forceinline__ float block_sum(float v, float* sm) {
#pragma unroll
  for (int o = 32; o > 0; o >>= 1) v += __shfl_xor(v, o, 64);
  int w = threadIdx.x >> 6;
  __syncthreads();
  if ((threadIdx.x & 63) == 0) sm[w] = v;
  __syncthreads();
  return sm[0] + sm[1] + sm[2] + sm[3];
}

__global__ __launch_bounds__(256) void ln_phase_kernel(
    const float* __restrict__ x, const float* __restrict__ Wp,
    const float* __restrict__ gamma, const float* __restrict__ beta,
    unsigned short* __restrict__ xn, float* __restrict__ cosP,
    float* __restrict__ sinP) {
  __shared__ float sm[4];
  int row = blockIdx.x;
  int tid = threadIdx.x;
  float4 v = ((const float4*)(x + (size_t)row * D_MODEL))[tid];
  float mu = block_sum(v.x + v.y + v.z + v.w, sm) * (1.0f / D_MODEL);
  float d0 = v.x - mu, d1 = v.y - mu, d2 = v.z - mu, d3 = v.w - mu;
  float var = block_sum(d0 * d0 + d1 * d1 + d2 * d2 + d3 * d3, sm) * (1.0f / D_MODEL);
  float rinv = rsqrtf(var + 1e-5f);
  float4 g = ((const float4*)gamma)[tid];
  float4 be = ((const float4*)beta)[tid];
  float n0 = d0 * rinv * g.x + be.x;
  float n1 = d1 * rinv * g.y + be.y;
  float n2 = d2 * rinv * g.z + be.z;
  float n3 = d3 * rinv * g.w + be.w;
  ushort4 p;
  p.x = f2bf(n0); p.y = f2bf(n1); p.z = f2bf(n2); p.w = f2bf(n3);
  ((ushort4*)(xn + (size_t)row * D_MODEL))[tid] = p;
  float4 wp = ((const float4*)Wp)[tid];
  float ph = block_sum(n0 * wp.x + n1 * wp.y + n2 * wp.z + n3 * wp.w, sm);
  if (tid == 0) {
    cosP[row] = cosf(ph);
    sinP[row] = sinf(ph);
  }
}

// ---------------- kernel 2b: fill K' phase columns (64..79) ----------------
__global__ __launch_bounds__(256) void phase_fill_kernel(
    const float* __restrict__ cosP, const float* __restrict__ sinP,
    unsigned short* __restrict__ kk80) {
  int gid = blockIdx.x * 256 + threadIdx.x;  // 65536 (bh,s) rows
  int s = gid & (S_LEN - 1);
  int bh = gid >> 11;
  int b = bh >> 4;
  int tok = b * S_LEN + s;
  unsigned int w0 = (unsigned int)f2bf(cosP[tok]) | ((unsigned int)f2bf(sinP[tok]) << 16);
  int4 lo = make_int4((int)w0, 0, 0, 0);
  int4 hi = make_int4(0, 0, 0, 0);
  *(int4*)(kk80 + (size_t)gid * DK + 64) = lo;
  *(int4*)(kk80 + (size_t)gid * DK + 72) = hi;
}

// ---------------- kernel 3: QKV GEMM (NT, 128x64 tiles, BK=64, async) --------
// z=0: Q = xn Wq^T (scaled 0.125*log2e)  z=1: K -> kk80 (stride 80)
// z=2: vT = Wv xn^T (operand swap -> coalesced transposed store)
__global__ __launch_bounds__(256) void qkv_gemm_kernel(
    const unsigned short* __restrict__ xn, const unsigned short* __restrict__ wbf,
    unsigned short* __restrict__ q, unsigned short* __restrict__ kk80,
    unsigned short* __restrict__ vT) {
  __shared__ __align__(16) unsigned short As[128 * 64];
  __shared__ __align__(16) unsigned short Bs[64 * 64];
  int z = blockIdx.z;
  const unsigned short* Wm = wbf + (size_t)z * (D_MODEL * D_MODEL);
  const unsigned short* Ap = (z == 2) ? Wm : xn;
  const unsigned short* Bp = (z == 2) ? xn : Wm;
  int bx = blockIdx.x, by = blockIdx.y;
  // z!=2: M=4096 (tok) x N=1024 (e);  z==2: M=1024 (e) x N=4096 (tok)
  int m0 = (z == 2) ? (bx >> 1) * 128 : by * 128;
  int n0 = (z == 2) ? (by * 2 + (bx & 1)) * 64 : bx * 64;
  int tid = threadIdx.x;
  int wave = tid >> 6, lane = tid & 63, quad = lane >> 4, l15 = lane & 15;
  int wm = (wave & 1) * 64, wn = (wave >> 1) * 32;
  f32x4 acc[4][2];
#pragma unroll
  for (int r = 0; r < 4; ++r)
#pragma unroll
    for (int c = 0; c < 2; ++c) acc[r][c] = (f32x4){0.f, 0.f, 0.f, 0.f};

  for (int k0 = 0; k0 < D_MODEL; k0 += 64) {
    __syncthreads();
#pragma unroll
    for (int t = 0; t < 4; ++t) {
      int c = t * 256 + tid;
      int r = c >> 3, p = c & 7;
      int qc = p ^ (r & 7);
      gl16(&Ap[(size_t)(m0 + r) * D_MODEL + k0 + qc * 8], &As[c * 8]);
    }
#pragma unroll
    for (int t = 0; t < 2; ++t) {
      int c = t * 256 + tid;
      int r = c >> 3, p = c & 7;
      int qc = p ^ (r & 7);
      gl16(&Bp[(size_t)(n0 + r) * D_MODEL + k0 + qc * 8], &Bs[c * 8]);
    }
    __syncthreads();
    bf16x8 af[4][2], bfr[2][2];
#pragma unroll
    for (int r = 0; r < 4; ++r) {
      int R = wm + r * 16 + l15;
#pragma unroll
      for (int h = 0; h < 2; ++h)
        af[r][h] = *(const bf16x8*)&As[R * 64 + ((h * 4 + quad) ^ (R & 7)) * 8];
    }
#pragma unroll
    for (int c = 0; c < 2; ++c) {
      int R = wn + c * 16 + l15;
#pragma unroll
      for (int h = 0; h < 2; ++h)
        bfr[c][h] = *(const bf16x8*)&Bs[R * 64 + ((h * 4 + quad) ^ (R & 7)) * 8];
    }
#pragma unroll
    for (int h = 0; h < 2; ++h)
#pragma unroll
      for (int r = 0; r < 4; ++r)
#pragma unroll
        for (int c = 0; c < 2; ++c)
          acc[r][c] = __builtin_amdgcn_mfma_f32_16x16x32_bf16(af[r][h], bfr[c][h], acc[r][c], 0, 0, 0);
  }
#pragma unroll
  for (int r = 0; r < 4; ++r) {
#pragma unroll
    for (int c = 0; c < 2; ++c) {
#pragma unroll
      for (int rr = 0; rr < 4; ++rr) {
        if (z == 2) {
          int e = m0 + wm + r * 16 + quad * 4 + rr;
          int tok = n0 + wn + c * 16 + l15;
          int hh = e >> 6, d = e & 63;
          int bb = tok >> 11, ss = tok & (S_LEN - 1);
          vT[(((size_t)(bb * NH + hh)) * DH + d) * S_LEN + ss] = f2bf(acc[r][c][rr]);
        } else {
          int tok = m0 + wm + r * 16 + quad * 4 + rr;
          int e = n0 + wn + c * 16 + l15;
          int hh = e >> 6, d = e & 63;
          int bb = tok >> 11, ss = tok & (S_LEN - 1);
          if (z == 0) {
            unsigned short val = f2bf(acc[r][c][rr] * (0.125f * LOG2E));
            q[(((size_t)(bb * NH + hh)) * S_LEN + ss) * DH + d] = val;
          } else {
            kk80[(((size_t)(bb * NH + hh)) * S_LEN + ss) * DK + d] = f2bf(acc[r][c][rr]);
          }
        }
      }
    }
  }
}

// ---------------- kernel 4: flash attention, 32x32 MFMA, intra-block j-split --
// 8 waves: wave-group g = wave>>2 handles j-half g for q-subtile (wave&3)*32.
// Partial O/l merged through LDS at the end. S^T = K'.Q'^T with resonance
// folded as 2 extra K-dims; exp2 fixed-max softmax; per-lane row sums.
__global__ __launch_bounds__(512) void attn_kernel(
    const unsigned short* __restrict__ q, const unsigned short* __restrict__ kk80,
    const unsigned short* __restrict__ vT, const float* __restrict__ cosP,
    const float* __restrict__ sinP, const float* __restrict__ carrier,
    const float* __restrict__ lamp, unsigned short* __restrict__ outw,
    float* __restrict__ energy) {
  __shared__ __align__(16) unsigned short Ks[2][640 * 8];  // per-group K' tile
  __shared__ __align__(16) unsigned short Vs[2][512 * 8];  // per-group V tile
  __shared__ __align__(16) unsigned int Ps[8][32 * 34];    // per-wave P, stride 34 dw
  __shared__ float Lr[8][32];
  __shared__ float er[4];
  int qt = blockIdx.x, h = blockIdx.y, b = blockIdx.z;
  int bh = b * NH + h;
  int tid = threadIdx.x, wave = tid >> 6, lane = tid & 63;
  int half = lane >> 5, l31 = lane & 31;
  int grp = wave >> 2, wq = wave & 3;
  int tid2 = tid & 255;

  const unsigned short* kb = kk80 + (size_t)bh * S_LEN * DK;
  const unsigned short* vb = vT + (size_t)bh * DH * S_LEN;
  int qrow = qt * 128 + wq * 32 + l31;

  // Q fragments: B[n=i][k=d], d-blocks 0..3 from global, block 4 = phase cols
  bf16x8 bQ[5];
  {
    const unsigned short* qp = q + ((size_t)bh * S_LEN + qrow) * DH;
#pragma unroll
    for (int db = 0; db < 4; ++db)
      bQ[db] = *(const bf16x8*)(qp + db * 16 + half * 8);
    bf16x8 z8 = {0, 0, 0, 0, 0, 0, 0, 0};
    if (half == 0) {
      float hl2 = 0.5f * lamp[0] * LOG2E;
      z8[0] = (short)f2bf(hl2 * cosP[b * S_LEN + qrow]);
      z8[1] = (short)f2bf(hl2 * sinP[b * S_LEN + qrow]);
    }
    bQ[4] = z8;
  }

  f32x16 O0 = {}, O1 = {};
  float l_i = 0.f;

  for (int j0 = 0; j0 < S_LEN / 2; j0 += 64) {
    int jbase = grp * (S_LEN / 2) + j0;
    __syncthreads();
    // stage K' (640 chunks, rotate-swizzled) and V (512 chunks, XOR-swizzled)
    unsigned short* Ksg = &Ks[grp][0];
    unsigned short* Vsg = &Vs[grp][0];
#pragma unroll
    for (int t = 0; t < 2; ++t) {
      int cc = t * 256 + tid2;
      int r = (cc * 205) >> 11;  // cc/10
      int p = cc - r * 10;
      int g = p + ((r >> 2) & 3);
      if (g >= 10) g -= 10;
      gl16(&kb[(size_t)(jbase + r) * DK + g * 8], Ksg + cc * 8);
    }
    if (tid2 < 128) {
      int cc = 512 + tid2;
      int r = (cc * 205) >> 11;
      int p = cc - r * 10;
      int g = p + ((r >> 2) & 3);
      if (g >= 10) g -= 10;
      gl16(&kb[(size_t)(jbase + r) * DK + g * 8], Ksg + cc * 8);
    }
#pragma unroll
    for (int t = 0; t < 2; ++t) {
      int cc = t * 256 + tid2;
      int r = cc >> 3, p = cc & 7;
      int g = p ^ (r & 7);
      gl16(&vb[(size_t)r * S_LEN + jbase + g * 8], Vsg + cc * 8);
    }
    __syncthreads();

    // S^T: A = K' (m=j), B = Q' (n=i); 2 j-subtiles x 5 d-blocks
    f32x16 Sf[2];
#pragma unroll
    for (int sj = 0; sj < 2; ++sj) {
      Sf[sj] = (f32x16){};
      int r = sj * 32 + l31;
      int rot = (r >> 2) & 3;
#pragma unroll
      for (int db = 0; db < 5; ++db) {
        int p = db * 2 + half - rot;
        if (p < 0) p += 10;
        bf16x8 aK = *(const bf16x8*)(Ksg + (r * 10 + p) * 8);
        Sf[sj] = __builtin_amdgcn_mfma_f32_32x32x16_bf16(aK, bQ[db], Sf[sj], 0, 0, 0);
      }
    }

    // exp2 (fixed max), per-lane row-sum accumulate, pack j-pairs -> Ps
#pragma unroll
    for (int sj = 0; sj < 2; ++sj) {
#pragma unroll
      for (int rr = 0; rr < 8; ++rr) {
        float e0 = exp2f(Sf[sj][rr * 2 + 0]);
        float e1 = exp2f(Sf[sj][rr * 2 + 1]);
        l_i += e0 + e1;
        __hip_bfloat162 pk = __float22bfloat162_rn(float2{e0, e1});
        int jd = sj * 16 + (rr >> 1) * 4 + half * 2 + (rr & 1);
        Ps[wave][l31 * 34 + jd] = *(unsigned int*)&pk;
      }
    }

    // O += P.V : A = P (m=i) from Ps, B = V^T (n=d) from Vs
#pragma unroll
    for (int jb = 0; jb < 4; ++jb) {
      const unsigned int* pp = &Ps[wave][l31 * 34 + jb * 8 + half * 4];
      uint2 a0 = *(const uint2*)pp;
      uint2 a1 = *(const uint2*)(pp + 2);
      union { unsigned int u[4]; bf16x8 v; } cvt;
      cvt.u[0] = a0.x; cvt.u[1] = a0.y; cvt.u[2] = a1.x; cvt.u[3] = a1.y;
      {
        int rv = l31;
        int p = (jb * 2 + half) ^ (rv & 7);
        bf16x8 bV = *(const bf16x8*)(Vsg + (rv * 8 + p) * 8);
        O0 = __builtin_amdgcn_mfma_f32_32x32x16_bf16(cvt.v, bV, O0, 0, 0, 0);
      }
      {
        int rv = 32 + l31;
        int p = (jb * 2 + half) ^ (rv & 7);
        bf16x8 bV = *(const bf16x8*)(Vsg + (rv * 8 + p) * 8);
        O1 = __builtin_amdgcn_mfma_f32_32x32x16_bf16(cvt.v, bV, O1, 0, 0, 0);
      }
    }
  }

  // merge partials across wave-groups through LDS (reuse Ps area)
  __syncthreads();
  l_i += __shfl_xor(l_i, 32, 64);
  Lr[wave][l31] = l_i;
  float* Om = (float*)&Ps[0][0];  // 4 pairs x 32 rows x 64 cols fp32 = 32 KB
  if (grp == 1) {
#pragma unroll
    for (int reg = 0; reg < 16; ++reg) {
      int ir = (reg & 3) + 8 * (reg >> 2) + 4 * half;
      Om[wq * 2048 + ir * 64 + l31] = O0[reg];
      Om[wq * 2048 + ir * 64 + 32 + l31] = O1[reg];
    }
  }
  __syncthreads();
  float esum = 0.f;
  if (grp == 0) {
    float ch = cosf(carrier[h]), sh = sinf(carrier[h]);
#pragma unroll
    for (int reg = 0; reg < 16; ++reg) {
      int ir = (reg & 3) + 8 * (reg >> 2) + 4 * half;
      int srow = qt * 128 + wq * 32 + ir;
      float v0 = O0[reg] + Om[wq * 2048 + ir * 64 + l31];
      float v1 = O1[reg] + Om[wq * 2048 + ir * 64 + 32 + l31];
      float lt = Lr[wq][ir] + Lr[wq + 4][ir];
      float cp = cosP[b * S_LEN + srow], sp = sinP[b * S_LEN + srow];
      float gate = 0.5f + 0.5f * (cp * ch + sp * sh);
      float gl = gate / lt;
      v0 *= gl; v1 *= gl;
      esum += fabsf(v0) + fabsf(v1);
      size_t tok = (size_t)b * S_LEN + srow;
      outw[tok * D_MODEL + h * DH + l31] = f2bf(v0);
      outw[tok * D_MODEL + h * DH + 32 + l31] = f2bf(v1);
    }
  }
#pragma unroll
  for (int off = 32; off > 0; off >>= 1) esum += __shfl_xor(esum, off, 64);
  if (lane == 0 && grp == 0) er[wave] = esum;
  __syncthreads();
  if (tid == 0) atomicAdd(energy, er[0] + er[1] + er[2] + er[3]);
}

// ---------------- kernel 5: output projection + residual (128x64, BK=64) -----
__global__ __launch_bounds__(256) void out_gemm_kernel(
    const unsigned short* __restrict__ A, const unsigned short* __restrict__ Wo,
    const float* __restrict__ x, float* __restrict__ y) {
  __shared__ __align__(16) unsigned short As[128 * 64];
  __shared__ __align__(16) unsigned short Bs[64 * 64];
  int tid = threadIdx.x;
  int wave = tid >> 6, lane = tid & 63, quad = lane >> 4, l15 = lane & 15;
  int wm = (wave & 1) * 64, wn = (wave >> 1) * 32;
  int m0 = blockIdx.y * 128, n0 = blockIdx.x * 64;
  f32x4 acc[4][2];
#pragma unroll
  for (int r = 0; r < 4; ++r)
#pragma unroll
    for (int c = 0; c < 2; ++c) acc[r][c] = (f32x4){0.f, 0.f, 0.f, 0.f};

  for (int k0 = 0; k0 < D_MODEL; k0 += 64) {
    __syncthreads();
#pragma unroll
    for (int t = 0; t < 4; ++t) {
      int c = t * 256 + tid;
      int r = c >> 3, p = c & 7;
      int qc = p ^ (r & 7);
      gl16(&A[(size_t)(m0 + r) * D_MODEL + k0 + qc * 8], &As[c * 8]);
    }
#pragma unroll
    for (int t = 0; t < 2; ++t) {
      int c = t * 256 + tid;
      int r = c >> 3, p = c & 7;
      int qc = p ^ (r & 7);
      gl16(&Wo[(size_t)(n0 + r) * D_MODEL + k0 + qc * 8], &Bs[c * 8]);
    }
    __syncthreads();
    bf16x8 af[4][2], bfr[2][2];
#pragma unroll
    for (int r = 0; r < 4; ++r) {
      int R = wm + r * 16 + l15;
#pragma unroll
      for (int h = 0; h < 2; ++h)
        af[r][h] = *(const bf16x8*)&As[R * 64 + ((h * 4 + quad) ^ (R & 7)) * 8];
    }
#pragma unroll
    for (int c = 0; c < 2; ++c) {
      int R = wn + c * 16 + l15;
#pragma unroll
      for (int h = 0; h < 2; ++h)
        bfr[c][h] = *(const bf16x8*)&Bs[R * 64 + ((h * 4 + quad) ^ (R & 7)) * 8];
    }
#pragma unroll
    for (int h = 0; h < 2; ++h)
#pragma unroll
      for (int r = 0; r < 4; ++r)
#pragma unroll
        for (int c = 0; c < 2; ++c)
          acc[r][c] = __builtin_amdgcn_mfma_f32_16x16x32_bf16(af[r][h], bfr[c][h], acc[r][c], 0, 0, 0);
  }
#pragma unroll
  for (int r = 0; r < 4; ++r) {
#pragma unroll
    for (int c = 0; c < 2; ++c) {
      int dcol = n0 + wn + c * 16 + l15;
#pragma unroll
      for (int rr = 0; rr < 4; ++rr) {
        int tok = m0 + wm + r * 16 + quad * 4 + rr;
        size_t idx = (size_t)tok * D_MODEL + dcol;
        y[idx] = x[idx] + acc[r][c][rr];
      }
    }
  }
}

extern "C" void kernel_launch(void* const* d_in, const int* in_sizes, int n_in,
                              void* d_out, int out_size, void* d_ws, size_t ws_size,
                              hipStream_t stream) {
  const float* x = (const float*)d_in[0];
  const float* Wq = (const float*)d_in[1];
  const float* Wk = (const float*)d_in[2];
  const float* Wv = (const float*)d_in[3];
  const float* Wo = (const float*)d_in[4];
  const float* Wp = (const float*)d_in[5];
  const float* gamma = (const float*)d_in[6];
  const float* beta = (const float*)d_in[7];
  const float* carrier = (const float*)d_in[8];
  const float* lam = (const float*)d_in[9];

  char* ws = (char*)d_ws;
  const size_t MB = 1024 * 1024;
  unsigned short* wbf = (unsigned short*)(ws);            // 8 MB
  unsigned short* xn = (unsigned short*)(ws + 8 * MB);    // 8 MB (aliased: outw)
  unsigned short* qq = (unsigned short*)(ws + 16 * MB);   // 8 MB (bh,S,64)
  unsigned short* kk80 = (unsigned short*)(ws + 24 * MB); // 10 MB (bh,S,80)
  unsigned short* vT = (unsigned short*)(ws + 34 * MB);   // 8 MB (bh,64,S)
  float* cosP = (float*)(ws + 42 * MB);                   // 16 KB
  float* sinP = (float*)(ws + 42 * MB + 16 * 1024);       // 16 KB
  unsigned short* outw = xn;  // attn runs after qkv consumed xn

  float* y = (float*)d_out;
  float* energy = y + (out_size - 1);

  prep_kernel<<<4096, 256, 0, stream>>>(Wq, Wk, Wv, Wo, wbf, energy);
  ln_phase_kernel<<<M_TOK, 256, 0, stream>>>(x, Wp, gamma, beta, xn, cosP, sinP);
  phase_fill_kernel<<<256, 256, 0, stream>>>(cosP, sinP, kk80);
  qkv_gemm_kernel<<<dim3(16, 32, 3), 256, 0, stream>>>(xn, wbf, qq, kk80, vT);
  attn_kernel<<<dim3(16, 16, 2), 512, 0, stream>>>(qq, kk80, vT, cosP, sinP,
                                                   carrier, lam, outw, energy);
  out_gemm_kernel<<<dim3(16, 32), 256, 0, stream>>>(outw, wbf + 3 * D_MODEL * D_MODEL,
                                                    x, y);
}

// Round 6
// 228.467 us; speedup vs baseline: 1.8182x; 1.0105x over previous
//
#include <hip/hip_runtime.h>
#include <hip/hip_bf16.h>

#define S_LEN 2048
#define D_MODEL 1024
#define NH 16
#define DH 64
#define M_TOK 4096  // B*S
#define DK 80       // K' row stride: 64 d + cos,sin + pad (cols 72..79 unused)

typedef __attribute__((ext_vector_type(8))) short bf16x8;
typedef __attribute__((ext_vector_type(4))) float f32x4;
typedef __attribute__((ext_vector_type(16))) float f32x16;

#define LOG2E 1.4426950408889634f

__device__ __forceinline__ unsigned short f2bf(float f) {
  unsigned u = __float_as_uint(f);
  u += 0x7FFF + ((u >> 16) & 1);  // RNE
  return (unsigned short)(u >> 16);
}

// async 16B global->LDS (LDS dst must be wave-uniform base + lane*16)
__device__ __forceinline__ void gl16(const void* g, void* l) {
  __builtin_amdgcn_global_load_lds(
      (const __attribute__((address_space(1))) unsigned int*)g,
      (__attribute__((address_space(3))) unsigned int*)l, 16, 0, 0);
}

// ---------------- kernel 1: cast weights to bf16, zero energy ----------------
__global__ __launch_bounds__(256) void prep_kernel(
    const float* __restrict__ Wq, const float* __restrict__ Wk,
    const float* __restrict__ Wv, const float* __restrict__ Wo,
    unsigned short* __restrict__ wbf, float* __restrict__ energy) {
  if (blockIdx.x == 0 && threadIdx.x == 0) *energy = 0.f;
  int idx = (blockIdx.x * 256 + threadIdx.x) * 4;
  int wsel = idx >> 20;
  const float* s = (wsel == 0) ? Wq : (wsel == 1) ? Wk : (wsel == 2) ? Wv : Wo;
  int off = idx & 1048575;
  float4 v = *(const float4*)(s + off);
  ushort4 p;
  p.x = f2bf(v.x); p.y = f2bf(v.y); p.z = f2bf(v.z); p.w = f2bf(v.w);
  *(ushort4*)(wbf + idx) = p;
}

// ---------------- kernel 2: LayerNorm + phase ----------------
__device__ __forceinline__ float block_sum(float v, float* sm) {
#pragma unroll
  for (int o = 32; o > 0; o >>= 1) v += __shfl_xor(v, o, 64);
  int w = threadIdx.x >> 6;
  __syncthreads();
  if ((threadIdx.x & 63) == 0) sm[w] = v;
  __syncthreads();
  return sm[0] + sm[1] + sm[2] + sm[3];
}

__global__ __launch_bounds__(256) void ln_phase_kernel(
    const float* __restrict__ x, const float* __restrict__ Wp,
    const float* __restrict__ gamma, const float* __restrict__ beta,
    unsigned short* __restrict__ xn, float* __restrict__ cosP,
    float* __restrict__ sinP) {
  __shared__ float sm[4];
  int row = blockIdx.x;
  int tid = threadIdx.x;
  float4 v = ((const float4*)(x + (size_t)row * D_MODEL))[tid];
  float mu = block_sum(v.x + v.y + v.z + v.w, sm) * (1.0f / D_MODEL);
  float d0 = v.x - mu, d1 = v.y - mu, d2 = v.z - mu, d3 = v.w - mu;
  float var = block_sum(d0 * d0 + d1 * d1 + d2 * d2 + d3 * d3, sm) * (1.0f / D_MODEL);
  float rinv = rsqrtf(var + 1e-5f);
  float4 g = ((const float4*)gamma)[tid];
  float4 be = ((const float4*)beta)[tid];
  float n0 = d0 * rinv * g.x + be.x;
  float n1 = d1 * rinv * g.y + be.y;
  float n2 = d2 * rinv * g.z + be.z;
  float n3 = d3 * rinv * g.w + be.w;
  ushort4 p;
  p.x = f2bf(n0); p.y = f2bf(n1); p.z = f2bf(n2); p.w = f2bf(n3);
  ((ushort4*)(xn + (size_t)row * D_MODEL))[tid] = p;
  float4 wp = ((const float4*)Wp)[tid];
  float ph = block_sum(n0 * wp.x + n1 * wp.y + n2 * wp.z + n3 * wp.w, sm);
  if (tid == 0) {
    cosP[row] = cosf(ph);
    sinP[row] = sinf(ph);
  }
}

// ---------------- kernel 2b: fill K' phase chunk (cols 64..71) ----------------
__global__ __launch_bounds__(256) void phase_fill_kernel(
    const float* __restrict__ cosP, const float* __restrict__ sinP,
    unsigned short* __restrict__ kk80) {
  int gid = blockIdx.x * 256 + threadIdx.x;  // 65536 (bh,s) rows
  int s = gid & (S_LEN - 1);
  int bh = gid >> 11;
  int b = bh >> 4;
  int tok = b * S_LEN + s;
  unsigned int w0 = (unsigned int)f2bf(cosP[tok]) | ((unsigned int)f2bf(sinP[tok]) << 16);
  *(int4*)(kk80 + (size_t)gid * DK + 64) = make_int4((int)w0, 0, 0, 0);
}

// ---------------- kernel 3: merged QKV GEMM (128x128 tiles, BK=64, async) -----
// bid<512: C = xn.[Wq|Wk]^T (M=4096 x N=2048); n>>10 routes Q vs K.
// bid>=512: vT = Wv.xn^T (operand swap -> coalesced transposed store).
__global__ __launch_bounds__(256, 3) void qkv_gemm_kernel(
    const unsigned short* __restrict__ xn, const unsigned short* __restrict__ wbf,
    unsigned short* __restrict__ q, unsigned short* __restrict__ kk80,
    unsigned short* __restrict__ vT) {
  __shared__ __align__(16) unsigned short As[128 * 64];
  __shared__ __align__(16) unsigned short Bs[128 * 64];
  int bid = blockIdx.x;
  bool vmode = bid >= 512;
  const unsigned short* Ap;
  const unsigned short* Bp;
  int m0, n0;
  if (!vmode) {
    m0 = (bid >> 4) * 128;          // token tile
    n0 = (bid & 15) * 128;          // e tile over stacked Wq|Wk
    Ap = xn; Bp = wbf;
  } else {
    int v2 = bid - 512;
    m0 = (v2 & 7) * 128;            // Wv row tile (e)
    n0 = (v2 >> 3) * 128;           // token tile
    Ap = wbf + 2 * D_MODEL * D_MODEL; Bp = xn;
  }
  int tid = threadIdx.x;
  int wave = tid >> 6, lane = tid & 63, quad = lane >> 4, l15 = lane & 15;
  int wm = (wave & 1) * 64, wn = (wave >> 1) * 64;
  f32x4 acc[4][4];
#pragma unroll
  for (int r = 0; r < 4; ++r)
#pragma unroll
    for (int c = 0; c < 4; ++c) acc[r][c] = (f32x4){0.f, 0.f, 0.f, 0.f};

  for (int k0 = 0; k0 < D_MODEL; k0 += 64) {
    __syncthreads();
#pragma unroll
    for (int t = 0; t < 4; ++t) {
      int c = t * 256 + tid;
      int r = c >> 3, p = c & 7;
      int g = p ^ (r & 7);
      gl16(&Ap[(size_t)(m0 + r) * D_MODEL + k0 + g * 8], &As[c * 8]);
      gl16(&Bp[(size_t)(n0 + r) * D_MODEL + k0 + g * 8], &Bs[c * 8]);
    }
    __syncthreads();
    bf16x8 af[4][2], bfr[4][2];
#pragma unroll
    for (int r = 0; r < 4; ++r) {
      int R = wm + r * 16 + l15;
#pragma unroll
      for (int h = 0; h < 2; ++h)
        af[r][h] = *(const bf16x8*)&As[R * 64 + ((h * 4 + quad) ^ (R & 7)) * 8];
    }
#pragma unroll
    for (int c = 0; c < 4; ++c) {
      int R = wn + c * 16 + l15;
#pragma unroll
      for (int h = 0; h < 2; ++h)
        bfr[c][h] = *(const bf16x8*)&Bs[R * 64 + ((h * 4 + quad) ^ (R & 7)) * 8];
    }
#pragma unroll
    for (int h = 0; h < 2; ++h)
#pragma unroll
      for (int r = 0; r < 4; ++r)
#pragma unroll
        for (int c = 0; c < 4; ++c)
          acc[r][c] = __builtin_amdgcn_mfma_f32_16x16x32_bf16(af[r][h], bfr[c][h], acc[r][c], 0, 0, 0);
  }
#pragma unroll
  for (int r = 0; r < 4; ++r) {
#pragma unroll
    for (int c = 0; c < 4; ++c) {
#pragma unroll
      for (int rr = 0; rr < 4; ++rr) {
        if (vmode) {
          int e = m0 + wm + r * 16 + quad * 4 + rr;
          int tok = n0 + wn + c * 16 + l15;
          int hh = e >> 6, d = e & 63;
          int bb = tok >> 11, ss = tok & (S_LEN - 1);
          vT[(((size_t)(bb * NH + hh)) * DH + d) * S_LEN + ss] = f2bf(acc[r][c][rr]);
        } else {
          int tok = m0 + wm + r * 16 + quad * 4 + rr;
          int n = n0 + wn + c * 16 + l15;
          int e = n & 1023;
          int hh = e >> 6, d = e & 63;
          int bb = tok >> 11, ss = tok & (S_LEN - 1);
          if ((n0 >> 10) == 0) {
            q[(((size_t)(bb * NH + hh)) * S_LEN + ss) * DH + d] =
                f2bf(acc[r][c][rr] * (0.125f * LOG2E));
          } else {
            kk80[(((size_t)(bb * NH + hh)) * S_LEN + ss) * DK + d] = f2bf(acc[r][c][rr]);
          }
        }
      }
    }
  }
}

// ---------------- kernel 4: flash attention, 2-wave blocks, 64 q-rows ---------
// S^T = K'.Q'^T (resonance folded as 2 extra K-dims), exp2 fixed-max softmax,
// per-lane row sums, P->LDS->A-frags, O = P.V. K' staged 9 chunks/row
// (zero chunk 9 dropped: Q-side half-1 zeros annihilate k=72..79 products).
__global__ __launch_bounds__(128, 3) void attn_kernel(
    const unsigned short* __restrict__ q, const unsigned short* __restrict__ kk80,
    const unsigned short* __restrict__ vT, const float* __restrict__ cosP,
    const float* __restrict__ sinP, const float* __restrict__ carrier,
    const float* __restrict__ lamp, unsigned short* __restrict__ outw,
    float* __restrict__ energy) {
  __shared__ __align__(16) unsigned short Ks[64 * 72];   // natural, stride 9 chunks
  __shared__ __align__(16) unsigned short Vs[512 * 8];   // Vs[d][j], XOR-swizzled
  __shared__ __align__(16) unsigned int Ps[2][32 * 34];  // per-wave P, stride 34 dw
  __shared__ float Lr[2][32];
  __shared__ float er[2];
  int qt = blockIdx.x, h = blockIdx.y, b = blockIdx.z;
  int bh = b * NH + h;
  int tid = threadIdx.x, wave = tid >> 6, lane = tid & 63;
  int half = lane >> 5, l31 = lane & 31;

  const unsigned short* kb = kk80 + (size_t)bh * S_LEN * DK;
  const unsigned short* vb = vT + (size_t)bh * DH * S_LEN;
  int qrow = qt * 64 + wave * 32 + l31;

  // Q fragments: B[n=i][k], d-blocks 0..3 from global, block 4 = phase cols
  bf16x8 bQ[5];
  {
    const unsigned short* qp = q + ((size_t)bh * S_LEN + qrow) * DH;
#pragma unroll
    for (int db = 0; db < 4; ++db)
      bQ[db] = *(const bf16x8*)(qp + db * 16 + half * 8);
    bf16x8 z8 = {0, 0, 0, 0, 0, 0, 0, 0};
    if (half == 0) {
      float hl2 = 0.5f * lamp[0] * LOG2E;
      z8[0] = (short)f2bf(hl2 * cosP[b * S_LEN + qrow]);
      z8[1] = (short)f2bf(hl2 * sinP[b * S_LEN + qrow]);
    }
    bQ[4] = z8;
  }

  f32x16 O0 = {}, O1 = {};
  float l_i = 0.f;

  for (int j0 = 0; j0 < S_LEN; j0 += 64) {
    __syncthreads();
    // stage K': 576 chunks, natural row-major (stride 144 B self-rotates banks)
#pragma unroll
    for (int t = 0; t < 4; ++t) {
      unsigned int cc = t * 128 + tid;
      unsigned int r = cc / 9u, p = cc - r * 9u;
      gl16(&kb[(size_t)(j0 + r) * DK + p * 8], (unsigned short*)Ks + cc * 8);
    }
    if (tid < 64) {
      unsigned int cc = 512 + tid;
      unsigned int r = cc / 9u, p = cc - r * 9u;
      gl16(&kb[(size_t)(j0 + r) * DK + p * 8], (unsigned short*)Ks + cc * 8);
    }
    // stage V: 512 chunks, XOR-swizzled
#pragma unroll
    for (int t = 0; t < 4; ++t) {
      int cc = t * 128 + tid;
      int r = cc >> 3, p = cc & 7;
      int g = p ^ (r & 7);
      gl16(&vb[(size_t)r * S_LEN + j0 + g * 8], (unsigned short*)Vs + cc * 8);
    }
    __syncthreads();

    // S^T: A = K' (m=j), B = Q' (n=i); 2 j-subtiles x 5 d-blocks
    f32x16 Sf[2];
#pragma unroll
    for (int sj = 0; sj < 2; ++sj) {
      Sf[sj] = (f32x16){};
      int r = sj * 32 + l31;
#pragma unroll
      for (int db = 0; db < 5; ++db) {
        int p = (db < 4) ? (db * 2 + half) : 8;  // db=4,half=1: don't-care (B zero)
        bf16x8 aK = *(const bf16x8*)((const unsigned short*)Ks + (r * 9 + p) * 8);
        Sf[sj] = __builtin_amdgcn_mfma_f32_32x32x16_bf16(aK, bQ[db], Sf[sj], 0, 0, 0);
      }
    }

    // exp2 (fixed max: scores bounded), per-lane row-sum, pack j-pairs -> Ps
#pragma unroll
    for (int sj = 0; sj < 2; ++sj) {
#pragma unroll
      for (int rr = 0; rr < 8; ++rr) {
        float e0 = exp2f(Sf[sj][rr * 2 + 0]);
        float e1 = exp2f(Sf[sj][rr * 2 + 1]);
        l_i += e0 + e1;
        __hip_bfloat162 pk = __float22bfloat162_rn(float2{e0, e1});
        int jd = sj * 16 + (rr >> 1) * 4 + half * 2 + (rr & 1);
        Ps[wave][l31 * 34 + jd] = *(unsigned int*)&pk;
      }
    }

    // O += P.V : A = P (m=i) from Ps, B = V^T (n=d) from Vs
#pragma unroll
    for (int jb = 0; jb < 4; ++jb) {
      const unsigned int* pp = &Ps[wave][l31 * 34 + jb * 8 + half * 4];
      uint2 a0 = *(const uint2*)pp;
      uint2 a1 = *(const uint2*)(pp + 2);
      union { unsigned int u[4]; bf16x8 v; } cvt;
      cvt.u[0] = a0.x; cvt.u[1] = a0.y; cvt.u[2] = a1.x; cvt.u[3] = a1.y;
      {
        int rv = l31;
        int p = (jb * 2 + half) ^ (rv & 7);
        bf16x8 bV = *(const bf16x8*)((const unsigned short*)Vs + (rv * 8 + p) * 8);
        O0 = __builtin_amdgcn_mfma_f32_32x32x16_bf16(cvt.v, bV, O0, 0, 0, 0);
      }
      {
        int rv = 32 + l31;
        int p = (jb * 2 + half) ^ (rv & 7);
        bf16x8 bV = *(const bf16x8*)((const unsigned short*)Vs + (rv * 8 + p) * 8);
        O1 = __builtin_amdgcn_mfma_f32_32x32x16_bf16(cvt.v, bV, O1, 0, 0, 0);
      }
    }
  }

  // epilogue: complete row sums, gate, normalize, store, energy
  l_i += __shfl_xor(l_i, 32, 64);
  Lr[wave][l31] = l_i;
  float ch = cosf(carrier[h]), sh = sinf(carrier[h]);
  float esum = 0.f;
#pragma unroll
  for (int reg = 0; reg < 16; ++reg) {
    int ir = (reg & 3) + 8 * (reg >> 2) + 4 * half;
    int srow = qt * 64 + wave * 32 + ir;
    float cp = cosP[b * S_LEN + srow], sp = sinP[b * S_LEN + srow];
    float gate = 0.5f + 0.5f * (cp * ch + sp * sh);
    float gl = gate / Lr[wave][ir];
    float v0 = O0[reg] * gl, v1 = O1[reg] * gl;
    esum += fabsf(v0) + fabsf(v1);
    size_t tok = (size_t)b * S_LEN + srow;
    outw[tok * D_MODEL + h * DH + l31] = f2bf(v0);
    outw[tok * D_MODEL + h * DH + 32 + l31] = f2bf(v1);
  }
#pragma unroll
  for (int off = 32; off > 0; off >>= 1) esum += __shfl_xor(esum, off, 64);
  if (lane == 0) er[wave] = esum;
  __syncthreads();
  if (tid == 0) atomicAdd(energy, er[0] + er[1]);
}

// ---------------- kernel 5: output projection + residual (128x64, BK=64) -----
__global__ __launch_bounds__(256) void out_gemm_kernel(
    const unsigned short* __restrict__ A, const unsigned short* __restrict__ Wo,
    const float* __restrict__ x, float* __restrict__ y) {
  __shared__ __align__(16) unsigned short As[128 * 64];
  __shared__ __align__(16) unsigned short Bs[64 * 64];
  int tid = threadIdx.x;
  int wave = tid >> 6, lane = tid & 63, quad = lane >> 4, l15 = lane & 15;
  int wm = (wave & 1) * 64, wn = (wave >> 1) * 32;
  int m0 = blockIdx.y * 128, n0 = blockIdx.x * 64;
  f32x4 acc[4][2];
#pragma unroll
  for (int r = 0; r < 4; ++r)
#pragma unroll
    for (int c = 0; c < 2; ++c) acc[r][c] = (f32x4){0.f, 0.f, 0.f, 0.f};

  for (int k0 = 0; k0 < D_MODEL; k0 += 64) {
    __syncthreads();
#pragma unroll
    for (int t = 0; t < 4; ++t) {
      int c = t * 256 + tid;
      int r = c >> 3, p = c & 7;
      int qc = p ^ (r & 7);
      gl16(&A[(size_t)(m0 + r) * D_MODEL + k0 + qc * 8], &As[c * 8]);
    }
#pragma unroll
    for (int t = 0; t < 2; ++t) {
      int c = t * 256 + tid;
      int r = c >> 3, p = c & 7;
      int qc = p ^ (r & 7);
      gl16(&Wo[(size_t)(n0 + r) * D_MODEL + k0 + qc * 8], &Bs[c * 8]);
    }
    __syncthreads();
    bf16x8 af[4][2], bfr[2][2];
#pragma unroll
    for (int r = 0; r < 4; ++r) {
      int R = wm + r * 16 + l15;
#pragma unroll
      for (int h = 0; h < 2; ++h)
        af[r][h] = *(const bf16x8*)&As[R * 64 + ((h * 4 + quad) ^ (R & 7)) * 8];
    }
#pragma unroll
    for (int c = 0; c < 2; ++c) {
      int R = wn + c * 16 + l15;
#pragma unroll
      for (int h = 0; h < 2; ++h)
        bfr[c][h] = *(const bf16x8*)&Bs[R * 64 + ((h * 4 + quad) ^ (R & 7)) * 8];
    }
#pragma unroll
    for (int h = 0; h < 2; ++h)
#pragma unroll
      for (int r = 0; r < 4; ++r)
#pragma unroll
        for (int c = 0; c < 2; ++c)
          acc[r][c] = __builtin_amdgcn_mfma_f32_16x16x32_bf16(af[r][h], bfr[c][h], acc[r][c], 0, 0, 0);
  }
#pragma unroll
  for (int r = 0; r < 4; ++r) {
#pragma unroll
    for (int c = 0; c < 2; ++c) {
      int dcol = n0 + wn + c * 16 + l15;
#pragma unroll
      for (int rr = 0; rr < 4; ++rr) {
        int tok = m0 + wm + r * 16 + quad * 4 + rr;
        size_t idx = (size_t)tok * D_MODEL + dcol;
        y[idx] = x[idx] + acc[r][c][rr];
      }
    }
  }
}

extern "C" void kernel_launch(void* const* d_in, const int* in_sizes, int n_in,
                              void* d_out, int out_size, void* d_ws, size_t ws_size,
                              hipStream_t stream) {
  const float* x = (const float*)d_in[0];
  const float* Wq = (const float*)d_in[1];
  const float* Wk = (const float*)d_in[2];
  const float* Wv = (const float*)d_in[3];
  const float* Wo = (const float*)d_in[4];
  const float* Wp = (const float*)d_in[5];
  const float* gamma = (const float*)d_in[6];
  const float* beta = (const float*)d_in[7];
  const float* carrier = (const float*)d_in[8];
  const float* lam = (const float*)d_in[9];

  char* ws = (char*)d_ws;
  const size_t MB = 1024 * 1024;
  unsigned short* wbf = (unsigned short*)(ws);            // 8 MB (Wq|Wk|Wv|Wo)
  unsigned short* xn = (unsigned short*)(ws + 8 * MB);    // 8 MB (aliased: outw)
  unsigned short* qq = (unsigned short*)(ws + 16 * MB);   // 8 MB (bh,S,64)
  unsigned short* kk80 = (unsigned short*)(ws + 24 * MB); // 10 MB (bh,S,80)
  unsigned short* vT = (unsigned short*)(ws + 34 * MB);   // 8 MB (bh,64,S)
  float* cosP = (float*)(ws + 42 * MB);                   // 16 KB
  float* sinP = (float*)(ws + 42 * MB + 16 * 1024);       // 16 KB
  unsigned short* outw = xn;  // attn runs after qkv consumed xn

  float* y = (float*)d_out;
  float* energy = y + (out_size - 1);

  prep_kernel<<<4096, 256, 0, stream>>>(Wq, Wk, Wv, Wo, wbf, energy);
  ln_phase_kernel<<<M_TOK, 256, 0, stream>>>(x, Wp, gamma, beta, xn, cosP, sinP);
  phase_fill_kernel<<<256, 256, 0, stream>>>(cosP, sinP, kk80);
  qkv_gemm_kernel<<<768, 256, 0, stream>>>(xn, wbf, qq, kk80, vT);
  attn_kernel<<<dim3(32, 16, 2), 128, 0, stream>>>(qq, kk80, vT, cosP, sinP,
                                                   carrier, lam, outw, energy);
  out_gemm_kernel<<<dim3(16, 32), 256, 0, stream>>>(outw, wbf + 3 * D_MODEL * D_MODEL,
                                                    x, y);
}